// Round 9
// baseline (209.728 us; speedup 1.0000x reference)
//
#include <hip/hip_runtime.h>

#define NN 100000
#define FB_SH 10                 // fine bucket shift: bucket = col >> 10
#define FB_N  1024               // nodes per bucket
#define NFB   98                 // ceil(100000/1024)
#define NBLK  256                // binning blocks
#define BH_TOT (NFB * NBLK)      // 25088

// bf16 helpers (RN-even)
static __device__ __forceinline__ unsigned short f2bf(float f) {
    unsigned u = __float_as_uint(f);
    u += 0x7fffu + ((u >> 16) & 1u);
    return (unsigned short)(u >> 16);
}
static __device__ __forceinline__ float bf2f(unsigned short h) {
    return __uint_as_float(((unsigned)h) << 16);
}

// ================= CSR build: stable two-pass counting sort =================

__global__ __launch_bounds__(256) void k_hist1(const int* __restrict__ coli,
                                               int* __restrict__ bhist, int E, int chunk) {
    __shared__ int h[NFB];
    for (int i = threadIdx.x; i < NFB; i += 256) h[i] = 0;
    __syncthreads();
    int bk = blockIdx.x;
    int beg = bk * chunk, end = min(E, beg + chunk);
    for (int e = beg + threadIdx.x; e < end; e += 256)
        atomicAdd(&h[coli[e] >> FB_SH], 1);
    __syncthreads();
    for (int i = threadIdx.x; i < NFB; i += 256)
        bhist[i * NBLK + bk] = h[i];   // bucket-major for the scan
}

__global__ __launch_bounds__(1024) void k_scanA(int* __restrict__ a,
                                                int* __restrict__ blksum, int n) {
    __shared__ int sh[1024];
    int i = blockIdx.x * 1024 + threadIdx.x;
    int v = (i < n) ? a[i] : 0;
    sh[threadIdx.x] = v;
    __syncthreads();
    #pragma unroll
    for (int d = 1; d < 1024; d <<= 1) {
        int t = (threadIdx.x >= d) ? sh[threadIdx.x - d] : 0;
        __syncthreads();
        sh[threadIdx.x] += t;
        __syncthreads();
    }
    if (i < n) a[i] = sh[threadIdx.x] - v;   // local exclusive
    if (threadIdx.x == 1023) blksum[blockIdx.x] = sh[1023];
}

__global__ void k_scanB(int* __restrict__ blksum, int nb, int* __restrict__ off, int E) {
    if (threadIdx.x == 0 && blockIdx.x == 0) {
        int s = 0;
        for (int b = 0; b < nb; ++b) { int t = blksum[b]; blksum[b] = s; s += t; }
        off[NN] = E;
    }
}

__global__ __launch_bounds__(256) void k_scanC(int* __restrict__ a,
                                               const int* __restrict__ blksum, int n) {
    int i = blockIdx.x * 256 + threadIdx.x;
    if (i < n) a[i] += blksum[i >> 10];
}

__global__ __launch_bounds__(256) void k_bin2(
    const int* __restrict__ rowi, const int* __restrict__ coli,
    const int* __restrict__ bbase, unsigned int* __restrict__ cbin, int E, int chunk)
{
    __shared__ int cur[NFB];
    int bk = blockIdx.x;
    for (int i = threadIdx.x; i < NFB; i += 256) cur[i] = bbase[i * NBLK + bk];
    __syncthreads();
    int beg = bk * chunk, end = min(E, beg + chunk);
    for (int e = beg + threadIdx.x; e < end; e += 256) {
        int col = coli[e];
        int row = rowi[e];
        int b = col >> FB_SH;
        unsigned int val = ((unsigned int)row << FB_SH) | (unsigned int)(col & (FB_N - 1));
        int pos = atomicAdd(&cur[b], 1);
        cbin[pos] = val;
    }
}

__global__ __launch_bounds__(1024) void k_csr(
    const unsigned int* __restrict__ cbin, const int* __restrict__ bbase,
    int* __restrict__ off, float* __restrict__ dinv,
    int* __restrict__ srcs, int n, int E)
{
    __shared__ int hist[FB_N];
    __shared__ int wsum[16];
    int b = blockIdx.x;
    int beg = bbase[b * NBLK];
    int end = (b + 1 < NFB) ? bbase[(b + 1) * NBLK] : E;
    int tid = threadIdx.x;
    hist[tid] = 0;
    __syncthreads();
    for (int e = beg + tid; e < end; e += 1024)
        atomicAdd(&hist[cbin[e] & (FB_N - 1)], 1);
    __syncthreads();
    int v = hist[tid];
    int lane = tid & 63;
    int wid  = tid >> 6;
    int incl = v;
    #pragma unroll
    for (int d = 1; d < 64; d <<= 1) {
        int t = __shfl_up(incl, d, 64);
        if (lane >= d) incl += t;
    }
    if (lane == 63) wsum[wid] = incl;
    __syncthreads();
    if (wid == 0) {
        int ws = (lane < 16) ? wsum[lane] : 0;
        int wincl = ws;
        #pragma unroll
        for (int d = 1; d < 16; d <<= 1) {
            int t = __shfl_up(wincl, d, 64);
            if (lane >= d) wincl += t;
        }
        if (lane < 16) wsum[lane] = wincl - ws;
    }
    __syncthreads();
    int excl = wsum[wid] + incl - v;
    int node = (b << FB_SH) + tid;
    if (node < n) {
        off[node]  = beg + excl;
        dinv[node] = rsqrtf((float)(v + 1));   // +1 self-loop
    }
    __syncthreads();
    hist[tid] = excl;   // becomes cursor
    __syncthreads();
    for (int e = beg + tid; e < end; e += 1024) {
        unsigned int pv = cbin[e];
        int cl  = (int)(pv & (FB_N - 1));
        int row = (int)(pv >> FB_SH);
        int p = atomicAdd(&hist[cl], 1);
        srcs[beg + p] = row;
    }
}

// ================= GEMM: Ybf = bf16((X @ W) * dinv[row]) =================
template<int DOUT>
__global__ __launch_bounds__(256) void k_gemm_scale(
    const float* __restrict__ X, const float* __restrict__ W,
    const float* __restrict__ dinv, unsigned short* __restrict__ Ybf, int n)
{
    constexpr int TPR = DOUT / 4;
    constexpr int R   = 256 / TPR;
    __shared__ float sW[64 * DOUT];
    __shared__ float sX[R * 64];

    for (int i = threadIdx.x; i < 64 * DOUT; i += 256) sW[i] = W[i];
    int r0 = blockIdx.x * R;
    for (int i = threadIdx.x; i < R * 64; i += 256) {
        int r = r0 + (i >> 6);
        sX[i] = (r < n) ? X[(size_t)r * 64 + (i & 63)] : 0.0f;
    }
    __syncthreads();

    int lr  = threadIdx.x / TPR;
    int c4  = (threadIdx.x % TPR) * 4;
    int row = r0 + lr;
    const float* xr = &sX[lr * 64];
    float4 acc = make_float4(0.f, 0.f, 0.f, 0.f);
    #pragma unroll
    for (int k = 0; k < 64; ++k) {
        float xv = xr[k];
        const float* wr = &sW[k * DOUT + c4];
        acc.x = fmaf(xv, wr[0], acc.x);
        acc.y = fmaf(xv, wr[1], acc.y);
        acc.z = fmaf(xv, wr[2], acc.z);
        acc.w = fmaf(xv, wr[3], acc.w);
    }
    if (row < n) {
        float s = dinv[row];
        ushort4 o;
        o.x = f2bf(acc.x * s);
        o.y = f2bf(acc.y * s);
        o.z = f2bf(acc.z * s);
        o.w = f2bf(acc.w * s);
        *(ushort4*)&Ybf[(size_t)row * DOUT + c4] = o;
    }
}

// ======== CSR aggregate: O = [relu](dinv[i]*(Y[i] + sum_in Y[src]) + b) ========
// D=64: one 64-lane wave per node; lane = (edge slot h 0/1, channel pair ch).
template<bool RELU>
__global__ __launch_bounds__(256) void k_agg64(
    const unsigned short* __restrict__ Ybf, const int* __restrict__ off,
    const int* __restrict__ srcs, const float* __restrict__ dinv,
    const float* __restrict__ bias, float* __restrict__ O, int n)
{
    int node = blockIdx.x * 4 + (threadIdx.x >> 6);
    if (node >= n) return;
    int l  = threadIdx.x & 63;
    int h  = l >> 5;             // edge slot (0/1)
    int ch = (l & 31) * 2;       // channel pair
    int beg = off[node], end = off[node + 1];
    float a0 = 0.f, a1 = 0.f;
    int j = beg;
    for (; j + 16 <= end; j += 16) {
        #pragma unroll
        for (int k = 0; k < 8; ++k) {
            int src = srcs[j + 2 * k + h];
            ushort2 u = *(const ushort2*)&Ybf[(size_t)src * 64 + ch];
            a0 += bf2f(u.x); a1 += bf2f(u.y);
        }
    }
    for (; j + 2 <= end; j += 2) {
        int src = srcs[j + h];
        ushort2 u = *(const ushort2*)&Ybf[(size_t)src * 64 + ch];
        a0 += bf2f(u.x); a1 += bf2f(u.y);
    }
    if (h == 0) {
        if (j < end) {   // odd leftover edge
            int src = srcs[j];
            ushort2 u = *(const ushort2*)&Ybf[(size_t)src * 64 + ch];
            a0 += bf2f(u.x); a1 += bf2f(u.y);
        }
        // self-loop
        ushort2 u = *(const ushort2*)&Ybf[(size_t)node * 64 + ch];
        a0 += bf2f(u.x); a1 += bf2f(u.y);
    }
    a0 += __shfl_xor(a0, 32, 64);
    a1 += __shfl_xor(a1, 32, 64);
    if (h == 0) {
        float d = dinv[node];
        float2 o;
        o.x = fmaf(d, a0, bias[ch]);
        o.y = fmaf(d, a1, bias[ch + 1]);
        if (RELU) { o.x = fmaxf(o.x, 0.f); o.y = fmaxf(o.y, 0.f); }
        *(float2*)&O[(size_t)node * 64 + ch] = o;
    }
}

// D=32: one 64-lane wave per node; lane = (edge slot q 0..3, channel pair ch).
template<bool RELU>
__global__ __launch_bounds__(256) void k_agg32(
    const unsigned short* __restrict__ Ybf, const int* __restrict__ off,
    const int* __restrict__ srcs, const float* __restrict__ dinv,
    const float* __restrict__ bias, float* __restrict__ O, int n)
{
    int node = blockIdx.x * 4 + (threadIdx.x >> 6);
    if (node >= n) return;
    int l  = threadIdx.x & 63;
    int q  = l >> 4;             // edge slot (0..3)
    int ch = (l & 15) * 2;       // channel pair
    int beg = off[node], end = off[node + 1];
    float a0 = 0.f, a1 = 0.f;
    int j = beg;
    for (; j + 16 <= end; j += 16) {
        #pragma unroll
        for (int k = 0; k < 4; ++k) {
            int src = srcs[j + 4 * k + q];
            ushort2 u = *(const ushort2*)&Ybf[(size_t)src * 32 + ch];
            a0 += bf2f(u.x); a1 += bf2f(u.y);
        }
    }
    for (; j + 4 <= end; j += 4) {
        int src = srcs[j + q];
        ushort2 u = *(const ushort2*)&Ybf[(size_t)src * 32 + ch];
        a0 += bf2f(u.x); a1 += bf2f(u.y);
    }
    if (q < end - j) {           // tail (0..3 edges)
        int src = srcs[j + q];
        ushort2 u = *(const ushort2*)&Ybf[(size_t)src * 32 + ch];
        a0 += bf2f(u.x); a1 += bf2f(u.y);
    }
    if (q == 0) {                // self-loop
        ushort2 u = *(const ushort2*)&Ybf[(size_t)node * 32 + ch];
        a0 += bf2f(u.x); a1 += bf2f(u.y);
    }
    a0 += __shfl_xor(a0, 16, 64);
    a1 += __shfl_xor(a1, 16, 64);
    a0 += __shfl_xor(a0, 32, 64);
    a1 += __shfl_xor(a1, 32, 64);
    if (q == 0) {
        float d = dinv[node];
        float2 o;
        o.x = fmaf(d, a0, bias[ch]);
        o.y = fmaf(d, a1, bias[ch + 1]);
        if (RELU) { o.x = fmaxf(o.x, 0.f); o.y = fmaxf(o.y, 0.f); }
        *(float2*)&O[(size_t)node * 32 + ch] = o;
    }
}

extern "C" void kernel_launch(void* const* d_in, const int* in_sizes, int n_in,
                              void* d_out, int out_size, void* d_ws, size_t ws_size,
                              hipStream_t stream) {
    const float* x  = (const float*)d_in[0];
    const int*   ei = (const int*)d_in[1];
    const float* W1 = (const float*)d_in[2];
    const float* b1 = (const float*)d_in[3];
    const float* W2 = (const float*)d_in[4];
    const float* b2 = (const float*)d_in[5];
    float* out = (float*)d_out;

    const int n = NN;
    const int E = in_sizes[1] / 2;
    const int* rowi = ei;
    const int* coli = ei + E;
    const int chunk = (E + NBLK - 1) / NBLK;

    // workspace layout, 256 B-aligned segments
    char* p = (char*)d_ws;
    auto alloc = [&p](size_t bytes) { char* q = p; p += (bytes + 255) & ~(size_t)255; return q; };
    int*   bhist  = (int*)alloc((size_t)BH_TOT * 4);
    int*   blksum = (int*)alloc(32 * 4);
    int*   off    = (int*)alloc((size_t)(n + 1) * 4);
    float* dinv   = (float*)alloc((size_t)n * 4);
    int*   srcs   = (int*)alloc((size_t)E * 4);
    unsigned short* Ybf1 = (unsigned short*)alloc((size_t)n * 64 * 2);
    unsigned short* Ybf2 = (unsigned short*)alloc((size_t)n * 32 * 2);
    float* H      = (float*)alloc((size_t)n * 64 * 4);
    unsigned int* cbin = (unsigned int*)H;   // alias: cbin dead before H written

    // ---- CSR build (counting sort, shared across both layers) ----
    k_hist1<<<NBLK, 256, 0, stream>>>(coli, bhist, E, chunk);
    int nbs = (BH_TOT + 1023) / 1024;   // 25
    k_scanA<<<nbs, 1024, 0, stream>>>(bhist, blksum, BH_TOT);
    k_scanB<<<1, 64, 0, stream>>>(blksum, nbs, off, E);
    k_scanC<<<(BH_TOT + 255) / 256, 256, 0, stream>>>(bhist, blksum, BH_TOT);
    k_bin2<<<NBLK, 256, 0, stream>>>(rowi, coli, bhist, cbin, E, chunk);
    k_csr<<<NFB, 1024, 0, stream>>>(cbin, bhist, off, dinv, srcs, n, E);

    // ---- layer 1 (in 64 -> hid 64, relu) ----
    k_gemm_scale<64><<<(n + 15) / 16, 256, 0, stream>>>(x, W1, dinv, Ybf1, n);
    k_agg64<true><<<(n + 3) / 4, 256, 0, stream>>>(Ybf1, off, srcs, dinv, b1, H, n);

    // ---- layer 2 (hid 64 -> out 32) ----
    k_gemm_scale<32><<<(n + 31) / 32, 256, 0, stream>>>(H, W2, dinv, Ybf2, n);
    k_agg32<false><<<(n + 3) / 4, 256, 0, stream>>>(Ybf2, off, srcs, dinv, b2, out, n);
}